// Round 1
// baseline (381.309 us; speedup 1.0000x reference)
//
#include <hip/hip_runtime.h>
#include <hip/hip_bf16.h>
#include <math.h>

// Problem constants (fixed by the reference)
#define BS 8
#define NQ 4096          // 64*64
#define E  256
#define NH 8
#define NP 4
#define HD 32            // E / NH
#define GW 64            // grid width  (W)
#define GH 64            // grid height (H)
#define T  (BS * NQ)     // 32768 tokens
#define NCAT 352         // 256 value + 64 off + 32 attn
#define NPAD 384         // padded to multiple of 64

// ---------------------------------------------------------------------------
// Kernel 0: concatenate projection weights into Wcat (NPAD x 256) + bcat
// layout: rows [0,256) = value_w, [256,320) = off_w, [320,352) = attn_w,
//         [352,384) = zero padding
// ---------------------------------------------------------------------------
__global__ __launch_bounds__(256) void cat_weights(
    const float* __restrict__ vw, const float* __restrict__ vb,
    const float* __restrict__ ow, const float* __restrict__ ob,
    const float* __restrict__ aw, const float* __restrict__ ab,
    float* __restrict__ Wcat, float* __restrict__ bcat)
{
    int i = blockIdx.x * 256 + threadIdx.x;
    if (i < NPAD * E) {
        int n = i >> 8, k = i & 255;
        float w = 0.f;
        if      (n < 256) w = vw[n * E + k];
        else if (n < 320) w = ow[(n - 256) * E + k];
        else if (n < 352) w = aw[(n - 320) * E + k];
        Wcat[i] = w;
    }
    if (i < NPAD) {
        float bv = 0.f;
        if      (i < 256) bv = vb[i];
        else if (i < 320) bv = ob[i - 256];
        else if (i < 352) bv = ab[i - 320];
        bcat[i] = bv;
    }
}

// ---------------------------------------------------------------------------
// Tiled fp32 GEMM:  C[t][n] = dot(X[t,:K], W[n,:K]) + bias[n]  (+ 2*resid)
// X: (T,K) row-major; W: (N,K) row-major (torch Linear convention)
// BM=64, BN=64, BK=16; 16x16 threads, each computes 4x4.
// N must be a multiple of 64 (padded); grid exact, no bounds checks.
// EPI==1: add 2*resid[t*K+n] (requires N==K==256).
// ---------------------------------------------------------------------------
#define BM 64
#define BN 64
#define BK 16

template <int EPI>
__global__ __launch_bounds__(256) void gemm_bias(
    const float* __restrict__ X, const float* __restrict__ W,
    const float* __restrict__ bias, const float* __restrict__ resid,
    float* __restrict__ C, int N, int K)
{
    __shared__ float As[BM][BK + 1];
    __shared__ float Bs[BK][BN + 1];

    const int bm = blockIdx.x * BM;
    const int bn = blockIdx.y * BN;
    const int tid = threadIdx.x;
    const int tx = tid & 15, ty = tid >> 4;

    float acc[4][4] = {};

    for (int k0 = 0; k0 < K; k0 += BK) {
        // load A tile: 64x16
        for (int i = tid; i < BM * BK; i += 256) {
            int r = i >> 4, c = i & 15;
            As[r][c] = X[(size_t)(bm + r) * K + k0 + c];
        }
        // load B tile: Bs[c][n] = W[bn+n][k0+c]
        for (int i = tid; i < BK * BN; i += 256) {
            int n = i & 63, c = i >> 6;
            Bs[c][n] = W[(size_t)(bn + n) * K + k0 + c];
        }
        __syncthreads();
#pragma unroll
        for (int k = 0; k < BK; ++k) {
            float a[4], b[4];
#pragma unroll
            for (int i = 0; i < 4; ++i) a[i] = As[ty * 4 + i][k];
#pragma unroll
            for (int j = 0; j < 4; ++j) b[j] = Bs[k][tx * 4 + j];
#pragma unroll
            for (int i = 0; i < 4; ++i)
#pragma unroll
                for (int j = 0; j < 4; ++j) acc[i][j] += a[i] * b[j];
        }
        __syncthreads();
    }

#pragma unroll
    for (int i = 0; i < 4; ++i) {
        int t = bm + ty * 4 + i;
#pragma unroll
        for (int j = 0; j < 4; ++j) {
            int n = bn + tx * 4 + j;
            float v = acc[i][j] + bias[n];
            if (EPI) v += 2.0f * resid[(size_t)t * K + n];
            C[(size_t)t * N + n] = v;
        }
    }
}

// ---------------------------------------------------------------------------
// Sampling kernel: one thread per (t, h, d).
// C holds the fused projection: per token row of NPAD floats:
//   [0,256)   value (h*32+d)
//   [256,320) offsets (h*8 + p*2 + {x,y})
//   [320,352) attn logits (h*4 + p)
// Value image for (b,h): pixel s=(y*64+x) at C[(b*4096+s)*NPAD + h*32 + d].
// Output S[t*256 + h*32 + d].
// ---------------------------------------------------------------------------
__global__ __launch_bounds__(256) void sample_kernel(
    const float* __restrict__ C, float* __restrict__ S)
{
    const int gid = blockIdx.x * 256 + threadIdx.x;
    const int d = gid & 31;
    const int h = (gid >> 5) & 7;
    const int t = gid >> 8;
    const int b = t >> 12;
    const int q = t & 4095;

    const float refx = (float)(q & 63) * (64.0f / 63.0f);
    const float refy = (float)(q >> 6) * (64.0f / 63.0f);

    const float* __restrict__ row = C + (size_t)t * NPAD;

    // softmax over the 4 attn logits of this head
    float l0 = row[320 + h * 4 + 0];
    float l1 = row[320 + h * 4 + 1];
    float l2 = row[320 + h * 4 + 2];
    float l3 = row[320 + h * 4 + 3];
    float m = fmaxf(fmaxf(l0, l1), fmaxf(l2, l3));
    float e0 = __expf(l0 - m), e1 = __expf(l1 - m);
    float e2 = __expf(l2 - m), e3 = __expf(l3 - m);
    float inv = 1.0f / (e0 + e1 + e2 + e3);
    float at[4] = {e0 * inv, e1 * inv, e2 * inv, e3 * inv};

    const float* __restrict__ vbase =
        C + (size_t)(b * NQ) * NPAD + h * HD + d;

    float acc = 0.f;
#pragma unroll
    for (int p = 0; p < NP; ++p) {
        float ox = row[256 + h * 8 + p * 2 + 0];
        float oy = row[256 + h * 8 + p * 2 + 1];
        float px = refx + ox - 0.5f;
        float py = refy + oy - 0.5f;
        float fx = floorf(px), fy = floorf(py);
        int x0 = (int)fx, y0 = (int)fy;
        float wx = px - fx, wy = py - fy;
        float a = at[p];

        float w00 = (1.f - wx) * (1.f - wy) * a;
        float w10 = wx * (1.f - wy) * a;
        float w01 = (1.f - wx) * wy * a;
        float w11 = wx * wy * a;

        int x1 = x0 + 1, y1 = y0 + 1;
        bool vx0 = (x0 >= 0) & (x0 < GW);
        bool vx1 = (x1 >= 0) & (x1 < GW);
        bool vy0 = (y0 >= 0) & (y0 < GH);
        bool vy1 = (y1 >= 0) & (y1 < GH);

        if (vy0 & vx0) acc += w00 * vbase[(size_t)(y0 * GW + x0) * NPAD];
        if (vy0 & vx1) acc += w10 * vbase[(size_t)(y0 * GW + x1) * NPAD];
        if (vy1 & vx0) acc += w01 * vbase[(size_t)(y1 * GW + x0) * NPAD];
        if (vy1 & vx1) acc += w11 * vbase[(size_t)(y1 * GW + x1) * NPAD];
    }

    S[(size_t)t * E + h * HD + d] = acc;
}

// ---------------------------------------------------------------------------
extern "C" void kernel_launch(void* const* d_in, const int* in_sizes, int n_in,
                              void* d_out, int out_size, void* d_ws, size_t ws_size,
                              hipStream_t stream)
{
    const float* query   = (const float*)d_in[0];
    const float* value_w = (const float*)d_in[1];
    const float* value_b = (const float*)d_in[2];
    const float* off_w   = (const float*)d_in[3];
    const float* off_b   = (const float*)d_in[4];
    const float* attn_w  = (const float*)d_in[5];
    const float* attn_b  = (const float*)d_in[6];
    const float* out_w   = (const float*)d_in[7];
    const float* out_b   = (const float*)d_in[8];

    float* ws   = (float*)d_ws;
    float* Wcat = ws;                       // NPAD*E
    float* bcat = Wcat + NPAD * E;          // NPAD
    float* C    = bcat + NPAD;              // T*NPAD
    float* S    = C + (size_t)T * NPAD;     // T*E

    cat_weights<<<(NPAD * E + 255) / 256, 256, 0, stream>>>(
        value_w, value_b, off_w, off_b, attn_w, attn_b, Wcat, bcat);

    dim3 g1(T / BM, NPAD / BN);
    gemm_bias<0><<<g1, 256, 0, stream>>>(query, Wcat, bcat, nullptr, C, NPAD, E);

    sample_kernel<<<T, 256, 0, stream>>>(C, S);

    dim3 g2(T / BM, E / BN);
    gemm_bias<1><<<g2, 256, 0, stream>>>(S, out_w, out_b, query, (float*)d_out, E, E);
}

// Round 2
// 79.471 us; speedup vs baseline: 4.7981x; 4.7981x over previous
//
#include <hip/hip_runtime.h>
#include <hip/hip_bf16.h>
#include <math.h>

// Problem constants (fixed by the reference)
#define BS 8
#define NQ 4096          // 64*64
#define E  256
#define NH 8
#define NP 4
#define HD 32
#define GW 64
#define GH 64
#define T  (BS * NQ)     // 32768
#define NPAD 384         // 256 value + 64 off + 32 attn + 32 pad

typedef __attribute__((ext_vector_type(8))) short bf16x8;   // MFMA A/B frag (4 VGPR)
typedef __attribute__((ext_vector_type(4))) float f32x4;    // MFMA C/D frag
typedef __attribute__((ext_vector_type(8))) unsigned short u16x8;

__device__ __forceinline__ float b2f(unsigned short u) {
    union { unsigned int i; float f; } x; x.i = ((unsigned int)u) << 16; return x.f;
}
__device__ __forceinline__ unsigned short f2b(float f) {
    __hip_bfloat16 h = __float2bfloat16(f);
    return *reinterpret_cast<unsigned short*>(&h);
}
__device__ __forceinline__ void gload16(const void* g, void* l) {
    __builtin_amdgcn_global_load_lds(
        (__attribute__((address_space(1))) void*)g,
        (__attribute__((address_space(3))) void*)l, 16, 0, 0);
}

// ---------------------------------------------------------------------------
// prep: Wcat (NPAD x 256 bf16), Wo (256x256 bf16), bcat (fp32 NPAD)
// Wcat rows: [0,256)=value_w, [256,320)=off_w, [320,352)=attn_w, [352,384)=0
// ---------------------------------------------------------------------------
__global__ __launch_bounds__(256) void prep_weights(
    const float* __restrict__ vw, const float* __restrict__ vb,
    const float* __restrict__ ow, const float* __restrict__ ob,
    const float* __restrict__ aw, const float* __restrict__ ab,
    const float* __restrict__ outw,
    unsigned short* __restrict__ Wcat, unsigned short* __restrict__ Wo,
    float* __restrict__ bcat)
{
    int i = blockIdx.x * 256 + threadIdx.x;
    if (i < NPAD * E) {
        int n = i >> 8, k = i & 255;
        float w = 0.f;
        if      (n < 256) w = vw[n * E + k];
        else if (n < 320) w = ow[(n - 256) * E + k];
        else if (n < 352) w = aw[(n - 320) * E + k];
        Wcat[i] = f2b(w);
    } else {
        int j = i - NPAD * E;
        if (j < E * E) Wo[j] = f2b(outw[j]);
    }
    if (i < NPAD) {
        float bv = 0.f;
        if      (i < 256) bv = vb[i];
        else if (i < 320) bv = ob[i - 256];
        else if (i < 352) bv = ab[i - 320];
        bcat[i] = bv;
    }
}

// fp32 -> bf16 vectorized convert (query)
__global__ __launch_bounds__(256) void conv_bf16(
    const float* __restrict__ in, unsigned short* __restrict__ out, int n4)
{
    int i = blockIdx.x * 256 + threadIdx.x;
    if (i >= n4) return;
    float4 v = *reinterpret_cast<const float4*>(&in[(size_t)i * 4]);
    ushort4 o;
    o.x = f2b(v.x); o.y = f2b(v.y); o.z = f2b(v.z); o.w = f2b(v.w);
    *reinterpret_cast<ushort4*>(&out[(size_t)i * 4]) = o;
}

// ---------------------------------------------------------------------------
// MFMA bf16 GEMM:  Out[t][n] = dot(A[t,:K], W[n,:K]) + bias[n] (+ 2*resid)
// A (M x K) bf16 row-major, W (N x K) bf16 row-major. 128x128 tile, 4 waves
// (2x2), each wave 64x64 = 4x4 fragments of 16x16, BK=32.
// LDS layout per operand: granule g = chunk*128 + row (16B granules), so
// global_load_lds's linear lane->LDS write matches [chunk][row][8bf16] and
// fragment ds_read_b128 is 16B-stride across lanes (2-way = conflict-free).
// MODE 0: bf16 store + bias.  MODE 1: f32 store + bias + 2*resid (N==K==256).
// ---------------------------------------------------------------------------
template <int MODE>
__global__ __launch_bounds__(256) void gemm_mfma(
    const unsigned short* __restrict__ A,
    const unsigned short* __restrict__ W,
    const float* __restrict__ bias,
    const float* __restrict__ resid,
    void* __restrict__ Out, int N, int K)
{
    __shared__ __align__(16) unsigned short lds[8192];  // A: [0,4096) B: [4096,8192)

    const int tid  = threadIdx.x;
    const int lane = tid & 63;
    const int wave = tid >> 6;
    const int wm = wave >> 1, wn = wave & 1;
    const int bm = blockIdx.x * 128;
    const int bn = blockIdx.y * 128;

    const int lrow   = lane & 15;
    const int lchunk = lane >> 4;

    f32x4 acc[4][4] = {};

    for (int k0 = 0; k0 < K; k0 += 32) {
#pragma unroll
        for (int p = 0; p < 2; ++p) {
            int g = p * 256 + wave * 64 + lane;
            int row = g & 127, chunk = g >> 7;
            unsigned short* la = &lds[(size_t)(p * 256 + wave * 64) * 8];
            gload16(A + (size_t)(bm + row) * K + k0 + chunk * 8, la);
            unsigned short* lb = &lds[4096 + (size_t)(p * 256 + wave * 64) * 8];
            gload16(W + (size_t)(bn + row) * K + k0 + chunk * 8, lb);
        }
        __syncthreads();

        bf16x8 af[4], bfr[4];
#pragma unroll
        for (int m = 0; m < 4; ++m)
            af[m] = *(const bf16x8*)&lds[(size_t)(lchunk * 128 + wm * 64 + m * 16 + lrow) * 8];
#pragma unroll
        for (int n = 0; n < 4; ++n)
            bfr[n] = *(const bf16x8*)&lds[4096 + (size_t)(lchunk * 128 + wn * 64 + n * 16 + lrow) * 8];

#pragma unroll
        for (int m = 0; m < 4; ++m)
#pragma unroll
            for (int n = 0; n < 4; ++n)
                acc[m][n] = __builtin_amdgcn_mfma_f32_16x16x32_bf16(
                    af[m], bfr[n], acc[m][n], 0, 0, 0);
        __syncthreads();
    }

    const int orow0 = (lane >> 4) * 4;
    const int ocol  = lane & 15;
#pragma unroll
    for (int m = 0; m < 4; ++m) {
#pragma unroll
        for (int n = 0; n < 4; ++n) {
            int colg = bn + wn * 64 + n * 16 + ocol;
            float bv = bias[colg];
#pragma unroll
            for (int r = 0; r < 4; ++r) {
                int rowg = bm + wm * 64 + m * 16 + orow0 + r;
                float v = acc[m][n][r] + bv;
                if (MODE == 0) {
                    ((unsigned short*)Out)[(size_t)rowg * N + colg] = f2b(v);
                } else {
                    v += 2.0f * resid[(size_t)rowg * N + colg];
                    ((float*)Out)[(size_t)rowg * N + colg] = v;
                }
            }
        }
    }
}

// ---------------------------------------------------------------------------
// Sampling: thread per (t, h, d-group of 8). C is bf16, per-token row NPAD:
//   [0,256) value, [256,320) offsets (h*8+p*2+{x,y}), [320,352) attn logits.
// ---------------------------------------------------------------------------
__global__ __launch_bounds__(256) void sample_kernel(
    const unsigned short* __restrict__ C, unsigned short* __restrict__ S)
{
    const int gid = blockIdx.x * 256 + threadIdx.x;
    const int d0 = gid & 3;          // 8-channel group
    const int h  = (gid >> 2) & 7;
    const int t  = gid >> 5;
    const int b  = t >> 12;
    const int q  = t & 4095;

    const float refx = (float)(q & 63) * (64.0f / 63.0f);
    const float refy = (float)(q >> 6) * (64.0f / 63.0f);

    const unsigned short* __restrict__ row = C + (size_t)t * NPAD;
    u16x8  offv = *(const u16x8*)&row[256 + h * 8];
    ushort4 lg  = *(const ushort4*)&row[320 + h * 4];

    float l0 = b2f(lg.x), l1 = b2f(lg.y), l2 = b2f(lg.z), l3 = b2f(lg.w);
    float m = fmaxf(fmaxf(l0, l1), fmaxf(l2, l3));
    float e0 = __expf(l0 - m), e1 = __expf(l1 - m);
    float e2 = __expf(l2 - m), e3 = __expf(l3 - m);
    float inv = 1.0f / (e0 + e1 + e2 + e3);
    float at[4] = {e0 * inv, e1 * inv, e2 * inv, e3 * inv};

    const unsigned short* __restrict__ vbase =
        C + (size_t)(b * NQ) * NPAD + h * HD + d0 * 8;

    float acc[8] = {};
#pragma unroll
    for (int p = 0; p < NP; ++p) {
        float ox = b2f(offv[2 * p]);
        float oy = b2f(offv[2 * p + 1]);
        float px = refx + ox - 0.5f;
        float py = refy + oy - 0.5f;
        float fx = floorf(px), fy = floorf(py);
        int x0 = (int)fx, y0 = (int)fy;
        float wx = px - fx, wy = py - fy;
        float a = at[p];

        float w00 = (1.f - wx) * (1.f - wy) * a;
        float w10 = wx * (1.f - wy) * a;
        float w01 = (1.f - wx) * wy * a;
        float w11 = wx * wy * a;

        int x1 = x0 + 1, y1 = y0 + 1;
        bool vx0 = (x0 >= 0) & (x0 < GW);
        bool vx1 = (x1 >= 0) & (x1 < GW);
        bool vy0 = (y0 >= 0) & (y0 < GH);
        bool vy1 = (y1 >= 0) & (y1 < GH);

#define CORNER(Y, X, WT)                                                     \
        {                                                                    \
            u16x8 g = *(const u16x8*)&vbase[(size_t)((Y) * GW + (X)) * NPAD];\
            _Pragma("unroll")                                                \
            for (int j = 0; j < 8; ++j) acc[j] += (WT) * b2f(g[j]);          \
        }
        if (vy0 & vx0) CORNER(y0, x0, w00);
        if (vy0 & vx1) CORNER(y0, x1, w10);
        if (vy1 & vx0) CORNER(y1, x0, w01);
        if (vy1 & vx1) CORNER(y1, x1, w11);
#undef CORNER
    }

    u16x8 o;
#pragma unroll
    for (int j = 0; j < 8; ++j) o[j] = f2b(acc[j]);
    *(u16x8*)&S[(size_t)t * E + h * HD + d0 * 8] = o;
}

// ---------------------------------------------------------------------------
extern "C" void kernel_launch(void* const* d_in, const int* in_sizes, int n_in,
                              void* d_out, int out_size, void* d_ws, size_t ws_size,
                              hipStream_t stream)
{
    const float* query   = (const float*)d_in[0];
    const float* value_w = (const float*)d_in[1];
    const float* value_b = (const float*)d_in[2];
    const float* off_w   = (const float*)d_in[3];
    const float* off_b   = (const float*)d_in[4];
    const float* attn_w  = (const float*)d_in[5];
    const float* attn_b  = (const float*)d_in[6];
    const float* out_w   = (const float*)d_in[7];
    const float* out_b   = (const float*)d_in[8];

    char* w = (char*)d_ws;
    unsigned short* Qb   = (unsigned short*)w;  w += (size_t)T * E * 2;      // 16 MB
    unsigned short* C    = (unsigned short*)w;  w += (size_t)T * NPAD * 2;   // 24 MB
    unsigned short* S    = (unsigned short*)w;  w += (size_t)T * E * 2;      // 16 MB
    unsigned short* Wcat = (unsigned short*)w;  w += (size_t)NPAD * E * 2;
    unsigned short* Wo   = (unsigned short*)w;  w += (size_t)E * E * 2;
    float*          bcat = (float*)w;

    prep_weights<<<(NPAD * E + E * E + 255) / 256, 256, 0, stream>>>(
        value_w, value_b, off_w, off_b, attn_w, attn_b, out_w, Wcat, Wo, bcat);

    conv_bf16<<<(T * E / 4 + 255) / 256, 256, 0, stream>>>(query, Qb, T * E / 4);

    dim3 g1(T / 128, NPAD / 128);
    gemm_mfma<0><<<g1, 256, 0, stream>>>(Qb, Wcat, bcat, nullptr, C, NPAD, E);

    sample_kernel<<<T * 32 / 256, 256, 0, stream>>>(C, S);

    dim3 g2(T / 128, E / 128);
    gemm_mfma<1><<<g2, 256, 0, stream>>>(S, Wo, out_b, query, d_out, E, E);
}